// Round 2
// baseline (246.163 us; speedup 1.0000x reference)
//
#include <hip/hip_runtime.h>

typedef unsigned short u16;
typedef unsigned int u32;
typedef __attribute__((ext_vector_type(8))) short bf16x8;
typedef __attribute__((ext_vector_type(4))) float f32x4;

#define HID 2048
#define S_LEN 1024
#define BATCH 2
#define G_KV 8
#define R_REP 4
#define HD 64
#define NQKV 3072  // 2048 q + 512 k + 512 v

__device__ __forceinline__ u16 f2bf(float f) {
    union { u32 u; float ff; } x; x.ff = f;
    u32 u = x.u;
    u += 0x7FFFu + ((u >> 16) & 1u);
    return (u16)(u >> 16);
}

__device__ __forceinline__ void gload_lds16(const void* g, void* l) {
    __builtin_amdgcn_global_load_lds((const __attribute__((address_space(1))) void*)g,
                                     (__attribute__((address_space(3))) void*)l,
                                     16, 0, 0);
}

// ------- fp32 -> bf16 bulk convert (x) -------
__global__ __launch_bounds__(256) void cvt_x(const float* __restrict__ in,
                                             u16* __restrict__ out) {
    int i = (blockIdx.x * 256 + threadIdx.x) * 8;
    float4 a = *(const float4*)(in + i);
    float4 b = *(const float4*)(in + i + 4);
    u16 t[8] = {f2bf(a.x), f2bf(a.y), f2bf(a.z), f2bf(a.w),
                f2bf(b.x), f2bf(b.y), f2bf(b.z), f2bf(b.w)};
    *(uint4*)(out + i) = *(const uint4*)t;
}

// ------- mask permute (S^T orientation): fp32 [B][S][S] -> fp32 fragment-order -------
__global__ __launch_bounds__(256) void mask_perm(const float* __restrict__ mask,
                                                 float* __restrict__ out) {
    __shared__ float tile[64 * 68];
    int bid = blockIdx.x;                 // 512 = B*16*16
    int kt = bid & 15, qblk = (bid >> 4) & 15, b = bid >> 8;
    int t = threadIdx.x;
    int row = t >> 2, c0 = (t & 3) * 16;
    const float* src = mask + ((size_t)b * S_LEN + qblk * 64 + row) * S_LEN + kt * 64 + c0;
#pragma unroll
    for (int i = 0; i < 4; ++i)
        *(float4*)&tile[row * 68 + c0 + i * 4] = *(const float4*)(src + i * 4);
    __syncthreads();
    int w = t >> 6, quad = (t >> 4) & 3, l16 = t & 15;
    int q = w * 16 + l16;
    float* dst = out + (size_t)bid * 4096 + t * 16;
#pragma unroll
    for (int mt = 0; mt < 4; ++mt) {
        float4 v = *(const float4*)&tile[q * 68 + mt * 16 + quad * 4];
        *(float4*)(dst + mt * 4) = v;
    }
}

// ------- Fused W transpose+convert: {Wq|Wk|Wv} fp32 [2048][*] -> WqkvT bf16 [3072][2048] -------
__global__ __launch_bounds__(256) void transpose_qkv(const float* __restrict__ Wq,
                                                     const float* __restrict__ Wk,
                                                     const float* __restrict__ Wv,
                                                     u16* __restrict__ out) {
    __shared__ float tile[32][33];
    int n0 = blockIdx.x * 32, k0 = blockIdx.y * 32;
    const float* in; int N, nc0;
    if (n0 < 2048)      { in = Wq; N = 2048; nc0 = n0; }
    else if (n0 < 2560) { in = Wk; N = 512;  nc0 = n0 - 2048; }
    else                { in = Wv; N = 512;  nc0 = n0 - 2560; }
    int tx = threadIdx.x, ty = threadIdx.y;
#pragma unroll
    for (int j = 0; j < 4; ++j)
        tile[ty + j * 8][tx] = in[(size_t)(k0 + ty + j * 8) * N + nc0 + tx];
    __syncthreads();
#pragma unroll
    for (int j = 0; j < 4; ++j)
        out[(size_t)(n0 + ty + j * 8) * 2048 + k0 + tx] = f2bf(tile[tx][ty + j * 8]);
}

// ------- Transpose+convert: in fp32 [K][N] -> out bf16 [N][K] -------
__global__ __launch_bounds__(256) void transpose_cvt(const float* __restrict__ in,
                                                     u16* __restrict__ out,
                                                     int K, int N) {
    __shared__ float tile[32][33];
    int n0 = blockIdx.x * 32, k0 = blockIdx.y * 32;
    int tx = threadIdx.x, ty = threadIdx.y;
#pragma unroll
    for (int j = 0; j < 4; ++j)
        tile[ty + j * 8][tx] = in[(size_t)(k0 + ty + j * 8) * N + n0 + tx];
    __syncthreads();
#pragma unroll
    for (int j = 0; j < 4; ++j)
        out[(size_t)(n0 + ty + j * 8) * K + k0 + tx] = f2bf(tile[tx][ty + j * 8]);
}

// ------- QKV GEMM: BM=64 BN=128 BK=32, 768 blocks (3/CU).
//         Depth-3 pipeline, NB=4 LDS buffers, counted vmcnt(6) — never drain to 0
//         in the main loop (T4). One raw s_barrier per K-step.
__global__ __launch_bounds__(256) void gemm_qkv(const u16* __restrict__ Xb,
                                                const u16* __restrict__ WT,
                                                const float* __restrict__ bq,
                                                const float* __restrict__ bk,
                                                const float* __restrict__ bv,
                                                u16* __restrict__ qb,
                                                u16* __restrict__ kb,
                                                u16* __restrict__ vb) {
    __shared__ __align__(16) u16 As[4][64 * 32];    // 16 KiB
    __shared__ __align__(16) u16 Bs[4][128 * 32];   // 32 KiB
    int tid = threadIdx.x;
    int w = tid >> 6, lane = tid & 63, quad = lane >> 4, l16 = lane & 15;
    int m0 = blockIdx.y * 64, n0 = blockIdx.x * 128;
    int wr = (w >> 1) * 32, wc = (w & 1) * 64;   // wave tile 32x64
    int srow = lane >> 2, scol = (lane & 3) * 8;

    // per-wave staging source pointers (k-advance by += 32)
    const u16* aP  = &Xb[(size_t)(m0 + w * 16 + srow) * 2048 + scol];
    const u16* bP0 = &WT[(size_t)(n0 + w * 32 + srow) * 2048 + scol];
    const u16* bP1 = &WT[(size_t)(n0 + w * 32 + 16 + srow) * 2048 + scol];
    // wave-uniform LDS staging bases
    u16* aL  = &As[0][(w * 16) * 32];
    u16* bL0 = &Bs[0][(w * 32) * 32];
    u16* bL1 = &Bs[0][(w * 32 + 16) * 32];

    f32x4 acc[2][4];
#pragma unroll
    for (int i = 0; i < 2; ++i)
#pragma unroll
        for (int j = 0; j < 4; ++j) acc[i][j] = (f32x4){0.f, 0.f, 0.f, 0.f};

    // prologue: stage tiles 0..2 into buffers 0..2 (9 loads in flight)
#pragma unroll
    for (int p = 0; p < 3; ++p) {
        int ko = p * 32;
        gload_lds16(aP + ko,  aL  + p * (64 * 32));
        gload_lds16(bP0 + ko, bL0 + p * (128 * 32));
        gload_lds16(bP1 + ko, bL1 + p * (128 * 32));
    }

#pragma unroll 4
    for (int t = 0; t < 64; ++t) {
        // tile-t's 3 loads (oldest) complete; tiles t+1,t+2 stay in flight
        asm volatile("s_waitcnt vmcnt(6)" ::: "memory");
        __builtin_amdgcn_s_barrier();            // all waves' tile-t now in LDS
        __builtin_amdgcn_sched_barrier(0);       // nothing crosses upward

        // stage tile t+3 into buf[(t+3)&3] (issued AFTER barrier: no overwrite race;
        // tail iterations re-stage tile 63 into a dead buffer to keep counts uniform)
        int tn = t + 3;
        int ko = (tn < 64 ? tn : 63) * 32;
        int bn = tn & 3;
        gload_lds16(aP + ko,  aL  + bn * (64 * 32));
        gload_lds16(bP0 + ko, bL0 + bn * (128 * 32));
        gload_lds16(bP1 + ko, bL1 + bn * (128 * 32));

        int cb = t & 3;
        bf16x8 af[2], bfr[4];
#pragma unroll
        for (int mt = 0; mt < 2; ++mt)
            af[mt] = *(const bf16x8*)&As[cb][(wr + mt * 16 + l16) * 32 + quad * 8];
#pragma unroll
        for (int nt = 0; nt < 4; ++nt)
            bfr[nt] = *(const bf16x8*)&Bs[cb][(wc + nt * 16 + l16) * 32 + quad * 8];
#pragma unroll
        for (int mt = 0; mt < 2; ++mt)
#pragma unroll
            for (int nt = 0; nt < 4; ++nt)
                acc[mt][nt] = __builtin_amdgcn_mfma_f32_16x16x32_bf16(af[mt], bfr[nt], acc[mt][nt], 0, 0, 0);
    }
    // drain dead-buffer stages before epilogue / endpgm (LDS dealloc safety)
    asm volatile("s_waitcnt vmcnt(0)" ::: "memory");

#pragma unroll
    for (int nt = 0; nt < 4; ++nt) {
        int n = n0 + wc + nt * 16 + l16;
        float bias;
        if (n < 2048) bias = bq[n];
        else if (n < 2560) bias = bk[n - 2048];
        else bias = bv[n - 2560];
#pragma unroll
        for (int mt = 0; mt < 2; ++mt) {
#pragma unroll
            for (int reg = 0; reg < 4; ++reg) {
                int m = m0 + wr + mt * 16 + quad * 4 + reg;
                float val = acc[mt][nt][reg] + bias;
                int b = m >> 10, s = m & 1023;
                if (n < 2048) {
                    int g = n >> 8, r = (n >> 6) & 3, d = n & 63;
                    qb[((((size_t)(b * G_KV + g) * R_REP + r) * S_LEN) + s) * HD + d] = f2bf(val * 0.125f);
                } else if (n < 2560) {
                    int n2 = n - 2048, g = n2 >> 6, d = n2 & 63;
                    kb[(((size_t)(b * G_KV + g) * S_LEN) + s) * HD + d] = f2bf(val);
                } else {
                    int n2 = n - 2560, g = n2 >> 6, d = n2 & 63;
                    vb[(((size_t)(b * G_KV + g) * HD + d) * S_LEN) + s] = f2bf(val);  // V^T
                }
            }
        }
    }
}

// ------- Attention: MFMA flash, S^T orientation (S^T = K·Q^T) -------
__global__ __launch_bounds__(256) void attn_mfma(const u16* __restrict__ qbuf,
                                                 const u16* __restrict__ kbuf,
                                                 const u16* __restrict__ vtbuf,
                                                 const float* __restrict__ mask_pm,
                                                 u16* __restrict__ aout) {
    __shared__ __align__(16) u16 Ks[64 * 72];   // [key][dim]
    __shared__ __align__(16) u16 Vs[64 * 72];   // [dim][key]
    __shared__ __align__(16) u16 Ps[64 * 72];   // [q][key] bf16 (wave-private strips)
    __shared__ float l_lds[64];

    int d = blockIdx.x;
    int xcd = d & 7, j = d >> 3;
    int pr = xcd * 2 + (j >> 6);          // (b,g) pair 0..15
    int r = (j >> 4) & 3, qblk = j & 15;
    int b = pr >> 3, g = pr & 7;

    int tid = threadIdx.x;
    int w = tid >> 6, lane = tid & 63, quad = lane >> 4, l16 = lane & 15;
    int s0 = qblk * 64;
    int q = w * 16 + l16;                 // this lane's softmax q-row

    const u16* qrow = qbuf +
        ((((size_t)(b * G_KV + g) * R_REP + r) * S_LEN) + s0 + q) * HD;
    bf16x8 qf0 = *(const bf16x8*)(qrow + quad * 8);
    bf16x8 qf1 = *(const bf16x8*)(qrow + 32 + quad * 8);

    f32x4 o_acc[4];
#pragma unroll
    for (int i = 0; i < 4; ++i) o_acc[i] = (f32x4){0.f, 0.f, 0.f, 0.f};
    float l_part = 0.f;

    const u16* kbase  = kbuf  + (size_t)(b * G_KV + g) * S_LEN * HD;
    const u16* vtbase = vtbuf + (size_t)(b * G_KV + g) * HD * S_LEN;
    const float* mbase = mask_pm + ((size_t)(b * 16 + qblk) * 16) * 4096 + tid * 16;

    int srow = tid >> 2, sc = (tid & 3) * 16;

    // prologue: prefetch tile 0
    uint4 kp0, kp1, vp0, vp1;
    f32x4 mc[4], mn[4];
    {
        const u16* kr = kbase + (size_t)srow * HD + sc;
        kp0 = *(const uint4*)kr; kp1 = *(const uint4*)(kr + 8);
        const u16* vr = vtbase + (size_t)srow * S_LEN + sc;
        vp0 = *(const uint4*)vr; vp1 = *(const uint4*)(vr + 8);
#pragma unroll
        for (int i = 0; i < 4; ++i) mc[i] = *(const f32x4*)(mbase + i * 4);
    }

    for (int kt = 0; kt < 16; ++kt) {
        __syncthreads();    // prior iteration's LDS reads complete
        *(uint4*)&Ks[srow * 72 + sc]     = kp0;
        *(uint4*)&Ks[srow * 72 + sc + 8] = kp1;
        *(uint4*)&Vs[srow * 72 + sc]     = vp0;
        *(uint4*)&Vs[srow * 72 + sc + 8] = vp1;
        __syncthreads();    // staging visible

        // prefetch kt+1 (overlaps compute)
        if (kt < 15) {
            int nk = (kt + 1) * 64;
            const u16* kr = kbase + (size_t)(nk + srow) * HD + sc;
            kp0 = *(const uint4*)kr; kp1 = *(const uint4*)(kr + 8);
            const u16* vr = vtbase + (size_t)srow * S_LEN + nk + sc;
            vp0 = *(const uint4*)vr; vp1 = *(const uint4*)(vr + 8);
            const float* mr = mbase + (size_t)(kt + 1) * 4096;
#pragma unroll
            for (int i = 0; i < 4; ++i) mn[i] = *(const f32x4*)(mr + i * 4);
        }

        // S^T = K * Q^T : A = K tile rows (keys), B = Q regs
#pragma unroll
        for (int mt = 0; mt < 4; ++mt) {
            bf16x8 af0 = *(const bf16x8*)&Ks[(mt * 16 + l16) * 72 + quad * 8];
            bf16x8 af1 = *(const bf16x8*)&Ks[(mt * 16 + l16) * 72 + 32 + quad * 8];
            f32x4 z = (f32x4){0.f, 0.f, 0.f, 0.f};
            z = __builtin_amdgcn_mfma_f32_16x16x32_bf16(af0, qf0, z, 0, 0, 0);
            f32x4 s = __builtin_amdgcn_mfma_f32_16x16x32_bf16(af1, qf1, s = z, 0, 0, 0);

            // softmax: 4 consecutive keys for this lane's q; round-half-up pack
            u32 er[4];
#pragma unroll
            for (int rg = 0; rg < 4; ++rg) {
                float e = __expf(s[rg] * mc[mt][rg]);
                u32 u = __float_as_uint(e) + 0x8000u;
                er[rg] = u;
                l_part += __uint_as_float(u & 0xFFFF0000u);  // consistent with stored P
            }
            uint2 pk;
            pk.x = __builtin_amdgcn_perm(er[1], er[0], 0x07060302u);
            pk.y = __builtin_amdgcn_perm(er[3], er[2], 0x07060302u);
            *(uint2*)&Ps[q * 72 + mt * 16 + quad * 4] = pk;   // wave-private strip
        }
        // no barrier: P strips are wave-private; in-wave DS ordering + lgkmcnt suffice

        // PV: O = P * V  (A = P fragments, B = V^T tiles)
        bf16x8 pf0 = *(const bf16x8*)&Ps[q * 72 + quad * 8];
        bf16x8 pf1 = *(const bf16x8*)&Ps[q * 72 + 32 + quad * 8];
#pragma unroll
        for (int nt = 0; nt < 4; ++nt) {
            bf16x8 vf0 = *(const bf16x8*)&Vs[(nt * 16 + l16) * 72 + quad * 8];
            bf16x8 vf1 = *(const bf16x8*)&Vs[(nt * 16 + l16) * 72 + 32 + quad * 8];
            o_acc[nt] = __builtin_amdgcn_mfma_f32_16x16x32_bf16(pf0, vf0, o_acc[nt], 0, 0, 0);
            o_acc[nt] = __builtin_amdgcn_mfma_f32_16x16x32_bf16(pf1, vf1, o_acc[nt], 0, 0, 0);
        }
        // rotate mask prefetch
#pragma unroll
        for (int i = 0; i < 4; ++i) mc[i] = mn[i];
    }

    // final l reduction: sum across quads (lanes with same l16), then in-wave transpose
    l_part += __shfl_xor(l_part, 16);
    l_part += __shfl_xor(l_part, 32);
    l_lds[w * 16 + l16] = l_part;        // wave-private strip write
    // read pattern below is same-wave; compiler orders DS ops

#pragma unroll
    for (int reg = 0; reg < 4; ++reg) {
        int row = w * 16 + quad * 4 + reg;
        float inv = 1.0f / l_lds[row];
        int sidx = s0 + row;
        u16* dst = aout + ((size_t)(b * S_LEN + sidx)) * HID + (g * R_REP + r) * HD;
#pragma unroll
        for (int nt = 0; nt < 4; ++nt)
            dst[nt * 16 + l16] = f2bf(o_acc[nt][reg] * inv);
    }
}

// ------- Output GEMM: BM=64 BN=128, 512 blocks (2/CU); depth-3 counted-vmcnt pipeline;
//         fp32 out + bias + residual -------
__global__ __launch_bounds__(256) void gemm_o(const u16* __restrict__ A,
                                              const u16* __restrict__ WT,
                                              const float* __restrict__ bo,
                                              const float* __restrict__ Xres,
                                              float* __restrict__ out) {
    __shared__ __align__(16) u16 As[4][64 * 32];
    __shared__ __align__(16) u16 Bs[4][128 * 32];
    int tid = threadIdx.x;
    int w = tid >> 6, lane = tid & 63, quad = lane >> 4, l16 = lane & 15;
    int m0 = blockIdx.y * 64, n0 = blockIdx.x * 128;
    int wr = (w >> 1) * 32, wc = (w & 1) * 64;
    int srow = lane >> 2, scol = (lane & 3) * 8;

    const u16* aP  = &A[(size_t)(m0 + w * 16 + srow) * 2048 + scol];
    const u16* bP0 = &WT[(size_t)(n0 + w * 32 + srow) * 2048 + scol];
    const u16* bP1 = &WT[(size_t)(n0 + w * 32 + 16 + srow) * 2048 + scol];
    u16* aL  = &As[0][(w * 16) * 32];
    u16* bL0 = &Bs[0][(w * 32) * 32];
    u16* bL1 = &Bs[0][(w * 32 + 16) * 32];

    f32x4 acc[2][4];
#pragma unroll
    for (int i = 0; i < 2; ++i)
#pragma unroll
        for (int j = 0; j < 4; ++j) acc[i][j] = (f32x4){0.f, 0.f, 0.f, 0.f};

#pragma unroll
    for (int p = 0; p < 3; ++p) {
        int ko = p * 32;
        gload_lds16(aP + ko,  aL  + p * (64 * 32));
        gload_lds16(bP0 + ko, bL0 + p * (128 * 32));
        gload_lds16(bP1 + ko, bL1 + p * (128 * 32));
    }

#pragma unroll 4
    for (int t = 0; t < 64; ++t) {
        asm volatile("s_waitcnt vmcnt(6)" ::: "memory");
        __builtin_amdgcn_s_barrier();
        __builtin_amdgcn_sched_barrier(0);

        int tn = t + 3;
        int ko = (tn < 64 ? tn : 63) * 32;
        int bn = tn & 3;
        gload_lds16(aP + ko,  aL  + bn * (64 * 32));
        gload_lds16(bP0 + ko, bL0 + bn * (128 * 32));
        gload_lds16(bP1 + ko, bL1 + bn * (128 * 32));

        int cb = t & 3;
        bf16x8 af[2], bfr[4];
#pragma unroll
        for (int mt = 0; mt < 2; ++mt)
            af[mt] = *(const bf16x8*)&As[cb][(wr + mt * 16 + l16) * 32 + quad * 8];
#pragma unroll
        for (int nt = 0; nt < 4; ++nt)
            bfr[nt] = *(const bf16x8*)&Bs[cb][(wc + nt * 16 + l16) * 32 + quad * 8];
#pragma unroll
        for (int mt = 0; mt < 2; ++mt)
#pragma unroll
            for (int nt = 0; nt < 4; ++nt)
                acc[mt][nt] = __builtin_amdgcn_mfma_f32_16x16x32_bf16(af[mt], bfr[nt], acc[mt][nt], 0, 0, 0);
    }
    asm volatile("s_waitcnt vmcnt(0)" ::: "memory");

#pragma unroll
    for (int nt = 0; nt < 4; ++nt) {
        int n = n0 + wc + nt * 16 + l16;
        float bias = bo[n];
#pragma unroll
        for (int mt = 0; mt < 2; ++mt) {
#pragma unroll
            for (int reg = 0; reg < 4; ++reg) {
                int m = m0 + wr + mt * 16 + quad * 4 + reg;
                out[(size_t)m * 2048 + n] = acc[mt][nt][reg] + bias + Xres[(size_t)m * 2048 + n];
            }
        }
    }
}

extern "C" void kernel_launch(void* const* d_in, const int* in_sizes, int n_in,
                              void* d_out, int out_size, void* d_ws, size_t ws_size,
                              hipStream_t stream) {
    const float* x    = (const float*)d_in[0];
    const float* mask = (const float*)d_in[1];
    const float* Wq   = (const float*)d_in[2];
    const float* bq   = (const float*)d_in[3];
    const float* Wk   = (const float*)d_in[4];
    const float* bk   = (const float*)d_in[5];
    const float* Wv   = (const float*)d_in[6];
    const float* bv   = (const float*)d_in[7];
    const float* Wo   = (const float*)d_in[8];
    const float* bo   = (const float*)d_in[9];
    float* out = (float*)d_out;

    u16* ws = (u16*)d_ws;
    size_t off = 0;
    u16* WqkvT = ws + off; off += (size_t)NQKV * 2048;
    u16* WoT   = ws + off; off += (size_t)2048 * 2048;
    u16* q_buf = ws + off; off += (size_t)BATCH * G_KV * R_REP * S_LEN * HD;
    u16* k_buf = ws + off; off += (size_t)BATCH * G_KV * S_LEN * HD;
    u16* v_buf = ws + off; off += (size_t)BATCH * G_KV * S_LEN * HD;  // transposed [b][g][d][s]
    u16* a_out = ws + off; off += (size_t)2048 * 2048;
    u16* Xb       = a_out;            // alias: consumed by gemm_qkv before attn writes a_out
    float* mask_pm = (float*)WqkvT;   // alias: WqkvT (12.6 MB) dead after gemm_qkv; need 8 MB

    cvt_x<<<dim3(2048 * 2048 / (256 * 8)), 256, 0, stream>>>(x, Xb);

    dim3 tb(32, 8);
    transpose_qkv<<<dim3(96, 64), tb, 0, stream>>>(Wq, Wk, Wv, WqkvT);
    transpose_cvt<<<dim3(64, 64), tb, 0, stream>>>(Wo, WoT, 2048, 2048);

    gemm_qkv<<<dim3(NQKV / 128, 2048 / 64), 256, 0, stream>>>(Xb, WqkvT, bq, bk, bv,
                                                              q_buf, k_buf, v_buf);

    mask_perm<<<dim3(BATCH * 16 * 16), 256, 0, stream>>>(mask, mask_pm);

    attn_mfma<<<dim3(BATCH * G_KV * R_REP * (S_LEN / 64)), 256, 0, stream>>>(
        q_buf, k_buf, v_buf, mask_pm, a_out);

    gemm_o<<<dim3(2048 / 128, 2048 / 64), 256, 0, stream>>>(a_out, WoT, bo, x, out);
}

// Round 4
// 243.511 us; speedup vs baseline: 1.0109x; 1.0109x over previous
//
#include <hip/hip_runtime.h>

typedef unsigned short u16;
typedef unsigned int u32;
typedef __attribute__((ext_vector_type(8))) short bf16x8;
typedef __attribute__((ext_vector_type(4))) float f32x4;

#define HID 2048
#define S_LEN 1024
#define BATCH 2
#define G_KV 8
#define R_REP 4
#define HD 64
#define NQKV 3072  // 2048 q + 512 k + 512 v

__device__ __forceinline__ u16 f2bf(float f) {
    union { u32 u; float ff; } x; x.ff = f;
    u32 u = x.u;
    u += 0x7FFFu + ((u >> 16) & 1u);
    return (u16)(u >> 16);
}

__device__ __forceinline__ void gload_lds16(const void* g, void* l) {
    __builtin_amdgcn_global_load_lds((const __attribute__((address_space(1))) void*)g,
                                     (__attribute__((address_space(3))) void*)l,
                                     16, 0, 0);
}

// ------- fp32 -> bf16 bulk convert (x) -------
__global__ __launch_bounds__(256) void cvt_x(const float* __restrict__ in,
                                             u16* __restrict__ out) {
    int i = (blockIdx.x * 256 + threadIdx.x) * 8;
    float4 a = *(const float4*)(in + i);
    float4 b = *(const float4*)(in + i + 4);
    u16 t[8] = {f2bf(a.x), f2bf(a.y), f2bf(a.z), f2bf(a.w),
                f2bf(b.x), f2bf(b.y), f2bf(b.z), f2bf(b.w)};
    *(uint4*)(out + i) = *(const uint4*)t;
}

// ------- mask permute (S^T orientation): fp32 [B][S][S] -> fp32 fragment-order -------
__global__ __launch_bounds__(256) void mask_perm(const float* __restrict__ mask,
                                                 float* __restrict__ out) {
    __shared__ float tile[64 * 68];
    int bid = blockIdx.x;                 // 512 = B*16*16
    int kt = bid & 15, qblk = (bid >> 4) & 15, b = bid >> 8;
    int t = threadIdx.x;
    int row = t >> 2, c0 = (t & 3) * 16;
    const float* src = mask + ((size_t)b * S_LEN + qblk * 64 + row) * S_LEN + kt * 64 + c0;
#pragma unroll
    for (int i = 0; i < 4; ++i)
        *(float4*)&tile[row * 68 + c0 + i * 4] = *(const float4*)(src + i * 4);
    __syncthreads();
    int w = t >> 6, quad = (t >> 4) & 3, l16 = t & 15;
    int q = w * 16 + l16;
    float* dst = out + (size_t)bid * 4096 + t * 16;
#pragma unroll
    for (int mt = 0; mt < 4; ++mt) {
        float4 v = *(const float4*)&tile[q * 68 + mt * 16 + quad * 4];
        *(float4*)(dst + mt * 4) = v;
    }
}

// ------- Fused W transpose+convert: {Wq|Wk|Wv} fp32 [2048][*] -> WqkvT bf16 [3072][2048] -------
__global__ __launch_bounds__(256) void transpose_qkv(const float* __restrict__ Wq,
                                                     const float* __restrict__ Wk,
                                                     const float* __restrict__ Wv,
                                                     u16* __restrict__ out) {
    __shared__ float tile[32][33];
    int n0 = blockIdx.x * 32, k0 = blockIdx.y * 32;
    const float* in; int N, nc0;
    if (n0 < 2048)      { in = Wq; N = 2048; nc0 = n0; }
    else if (n0 < 2560) { in = Wk; N = 512;  nc0 = n0 - 2048; }
    else                { in = Wv; N = 512;  nc0 = n0 - 2560; }
    int tx = threadIdx.x, ty = threadIdx.y;
#pragma unroll
    for (int j = 0; j < 4; ++j)
        tile[ty + j * 8][tx] = in[(size_t)(k0 + ty + j * 8) * N + nc0 + tx];
    __syncthreads();
#pragma unroll
    for (int j = 0; j < 4; ++j)
        out[(size_t)(n0 + ty + j * 8) * 2048 + k0 + tx] = f2bf(tile[tx][ty + j * 8]);
}

// ------- Transpose+convert: in fp32 [K][N] -> out bf16 [N][K] -------
__global__ __launch_bounds__(256) void transpose_cvt(const float* __restrict__ in,
                                                     u16* __restrict__ out,
                                                     int K, int N) {
    __shared__ float tile[32][33];
    int n0 = blockIdx.x * 32, k0 = blockIdx.y * 32;
    int tx = threadIdx.x, ty = threadIdx.y;
#pragma unroll
    for (int j = 0; j < 4; ++j)
        tile[ty + j * 8][tx] = in[(size_t)(k0 + ty + j * 8) * N + n0 + tx];
    __syncthreads();
#pragma unroll
    for (int j = 0; j < 4; ++j)
        out[(size_t)(n0 + ty + j * 8) * K + k0 + tx] = f2bf(tile[tx][ty + j * 8]);
}

// ------- QKV GEMM: BM=128 BN=96 BK=32, 512 blocks (2/CU exactly).
//         Wave tile 64x48 (4x3 frags): 7 ds_read_b128 feed 12 MFMA (was 6:8).
//         XOR-swizzled LDS (slot ^= (row>>1)&3 on 16B slots): conflict-free b128 reads.
//         Swizzle applied on the GLOBAL source of global_load_lds (dest stays linear)
//         and mirrored on the fragment-read address (G21: both-sides-or-neither).
__global__ __launch_bounds__(256) void gemm_qkv(const u16* __restrict__ Xb,
                                                const u16* __restrict__ WT,
                                                const float* __restrict__ bq,
                                                const float* __restrict__ bk,
                                                const float* __restrict__ bv,
                                                u16* __restrict__ qb,
                                                u16* __restrict__ kb,
                                                u16* __restrict__ vb) {
    __shared__ __align__(16) u16 As[2][128 * 32];   // 16 KiB
    __shared__ __align__(16) u16 Bs[2][96 * 32];    // 12 KiB
    int tid = threadIdx.x;
    int w = tid >> 6, lane = tid & 63, quad = lane >> 4, l16 = lane & 15;
    int m0 = blockIdx.y * 128, n0 = blockIdx.x * 96;
    int wr = (w >> 1) * 64, wc = (w & 1) * 48;   // wave tile 64x48
    int srow = lane >> 2;
    int scol = (((lane & 3) ^ ((lane >> 3) & 3)) * 8);   // swizzled global source col

    // staging sources: wave w stages A rows [w*32, w*32+32); waves 0-2 stage B rows [w*32, w*32+32)
    const u16* aP0 = &Xb[(size_t)(m0 + w * 32 + srow) * 2048 + scol];
    const u16* aP1 = aP0 + (size_t)16 * 2048;
    const u16* bP0 = &WT[(size_t)(n0 + (w < 3 ? w : 0) * 32 + srow) * 2048 + scol];
    const u16* bP1 = bP0 + (size_t)16 * 2048;

    f32x4 acc[4][3];
#pragma unroll
    for (int i = 0; i < 4; ++i)
#pragma unroll
        for (int j = 0; j < 3; ++j) acc[i][j] = (f32x4){0.f, 0.f, 0.f, 0.f};

    // prologue: stage tile 0 into buffer 0
    gload_lds16(aP0, &As[0][(w * 32) * 32]);
    gload_lds16(aP1, &As[0][(w * 32 + 16) * 32]);
    if (w < 3) {
        gload_lds16(bP0, &Bs[0][(w * 32) * 32]);
        gload_lds16(bP1, &Bs[0][(w * 32 + 16) * 32]);
    }
    __syncthreads();

    int rcol = (quad ^ ((l16 >> 1) & 3)) * 8;   // swizzled fragment-read col
    int cur = 0;
    for (int k0 = 0; k0 < 2048; k0 += 32) {
        int kn = k0 + 32;
        if (kn < 2048) {
            // prefetch next tile FIRST (flies under ds_read + MFMA)
            gload_lds16(aP0 + kn, &As[cur ^ 1][(w * 32) * 32]);
            gload_lds16(aP1 + kn, &As[cur ^ 1][(w * 32 + 16) * 32]);
            if (w < 3) {
                gload_lds16(bP0 + kn, &Bs[cur ^ 1][(w * 32) * 32]);
                gload_lds16(bP1 + kn, &Bs[cur ^ 1][(w * 32 + 16) * 32]);
            }
        }
        bf16x8 af[4], bfr[3];
#pragma unroll
        for (int mt = 0; mt < 4; ++mt)
            af[mt] = *(const bf16x8*)&As[cur][(wr + mt * 16 + l16) * 32 + rcol];
#pragma unroll
        for (int nt = 0; nt < 3; ++nt)
            bfr[nt] = *(const bf16x8*)&Bs[cur][(wc + nt * 16 + l16) * 32 + rcol];
#pragma unroll
        for (int mt = 0; mt < 4; ++mt)
#pragma unroll
            for (int nt = 0; nt < 3; ++nt)
                acc[mt][nt] = __builtin_amdgcn_mfma_f32_16x16x32_bf16(af[mt], bfr[nt], acc[mt][nt], 0, 0, 0);
        __syncthreads();   // drains this wave's prefetch (vmcnt0) + guards buffer reuse
        cur ^= 1;
    }

#pragma unroll
    for (int nt = 0; nt < 3; ++nt) {
        int n = n0 + wc + nt * 16 + l16;
        float bias;
        if (n < 2048) bias = bq[n];
        else if (n < 2560) bias = bk[n - 2048];
        else bias = bv[n - 2560];
#pragma unroll
        for (int mt = 0; mt < 4; ++mt) {
#pragma unroll
            for (int reg = 0; reg < 4; ++reg) {
                int m = m0 + wr + mt * 16 + quad * 4 + reg;
                float val = acc[mt][nt][reg] + bias;
                int b = m >> 10, s = m & 1023;
                if (n < 2048) {
                    int g = n >> 8, r = (n >> 6) & 3, d = n & 63;
                    qb[((((size_t)(b * G_KV + g) * R_REP + r) * S_LEN) + s) * HD + d] = f2bf(val * 0.125f);
                } else if (n < 2560) {
                    int n2 = n - 2048, g = n2 >> 6, d = n2 & 63;
                    kb[(((size_t)(b * G_KV + g) * S_LEN) + s) * HD + d] = f2bf(val);
                } else {
                    int n2 = n - 2560, g = n2 >> 6, d = n2 & 63;
                    vb[(((size_t)(b * G_KV + g) * HD + d) * S_LEN) + s] = f2bf(val);  // V^T
                }
            }
        }
    }
}

// ------- Attention: MFMA flash, S^T orientation (S^T = K·Q^T) -------
__global__ __launch_bounds__(256) void attn_mfma(const u16* __restrict__ qbuf,
                                                 const u16* __restrict__ kbuf,
                                                 const u16* __restrict__ vtbuf,
                                                 const float* __restrict__ mask_pm,
                                                 u16* __restrict__ aout) {
    __shared__ __align__(16) u16 Ks[64 * 72];   // [key][dim]
    __shared__ __align__(16) u16 Vs[64 * 72];   // [dim][key]
    __shared__ __align__(16) u16 Ps[64 * 72];   // [q][key] bf16 (wave-private strips)
    __shared__ float l_lds[64];

    int d = blockIdx.x;
    int xcd = d & 7, j = d >> 3;
    int pr = xcd * 2 + (j >> 6);          // (b,g) pair 0..15
    int r = (j >> 4) & 3, qblk = j & 15;
    int b = pr >> 3, g = pr & 7;

    int tid = threadIdx.x;
    int w = tid >> 6, lane = tid & 63, quad = lane >> 4, l16 = lane & 15;
    int s0 = qblk * 64;
    int q = w * 16 + l16;                 // this lane's softmax q-row

    const u16* qrow = qbuf +
        ((((size_t)(b * G_KV + g) * R_REP + r) * S_LEN) + s0 + q) * HD;
    bf16x8 qf0 = *(const bf16x8*)(qrow + quad * 8);
    bf16x8 qf1 = *(const bf16x8*)(qrow + 32 + quad * 8);

    f32x4 o_acc[4];
#pragma unroll
    for (int i = 0; i < 4; ++i) o_acc[i] = (f32x4){0.f, 0.f, 0.f, 0.f};
    float l_part = 0.f;

    const u16* kbase  = kbuf  + (size_t)(b * G_KV + g) * S_LEN * HD;
    const u16* vtbase = vtbuf + (size_t)(b * G_KV + g) * HD * S_LEN;
    const float* mbase = mask_pm + ((size_t)(b * 16 + qblk) * 16) * 4096 + tid * 16;

    int srow = tid >> 2, sc = (tid & 3) * 16;

    // prologue: prefetch tile 0
    uint4 kp0, kp1, vp0, vp1;
    f32x4 mc[4], mn[4];
    {
        const u16* kr = kbase + (size_t)srow * HD + sc;
        kp0 = *(const uint4*)kr; kp1 = *(const uint4*)(kr + 8);
        const u16* vr = vtbase + (size_t)srow * S_LEN + sc;
        vp0 = *(const uint4*)vr; vp1 = *(const uint4*)(vr + 8);
#pragma unroll
        for (int i = 0; i < 4; ++i) mc[i] = *(const f32x4*)(mbase + i * 4);
    }

    for (int kt = 0; kt < 16; ++kt) {
        __syncthreads();    // prior iteration's LDS reads complete
        *(uint4*)&Ks[srow * 72 + sc]     = kp0;
        *(uint4*)&Ks[srow * 72 + sc + 8] = kp1;
        *(uint4*)&Vs[srow * 72 + sc]     = vp0;
        *(uint4*)&Vs[srow * 72 + sc + 8] = vp1;
        __syncthreads();    // staging visible

        // prefetch kt+1 (overlaps compute)
        if (kt < 15) {
            int nk = (kt + 1) * 64;
            const u16* kr = kbase + (size_t)(nk + srow) * HD + sc;
            kp0 = *(const uint4*)kr; kp1 = *(const uint4*)(kr + 8);
            const u16* vr = vtbase + (size_t)srow * S_LEN + nk + sc;
            vp0 = *(const uint4*)vr; vp1 = *(const uint4*)(vr + 8);
            const float* mr = mbase + (size_t)(kt + 1) * 4096;
#pragma unroll
            for (int i = 0; i < 4; ++i) mn[i] = *(const f32x4*)(mr + i * 4);
        }

        // S^T = K * Q^T : A = K tile rows (keys), B = Q regs
#pragma unroll
        for (int mt = 0; mt < 4; ++mt) {
            bf16x8 af0 = *(const bf16x8*)&Ks[(mt * 16 + l16) * 72 + quad * 8];
            bf16x8 af1 = *(const bf16x8*)&Ks[(mt * 16 + l16) * 72 + 32 + quad * 8];
            f32x4 z = (f32x4){0.f, 0.f, 0.f, 0.f};
            z = __builtin_amdgcn_mfma_f32_16x16x32_bf16(af0, qf0, z, 0, 0, 0);
            f32x4 s = __builtin_amdgcn_mfma_f32_16x16x32_bf16(af1, qf1, s = z, 0, 0, 0);

            // softmax: 4 consecutive keys for this lane's q; round-half-up pack
            u32 er[4];
#pragma unroll
            for (int rg = 0; rg < 4; ++rg) {
                float e = __expf(s[rg] * mc[mt][rg]);
                u32 u = __float_as_uint(e) + 0x8000u;
                er[rg] = u;
                l_part += __uint_as_float(u & 0xFFFF0000u);  // consistent with stored P
            }
            uint2 pk;
            pk.x = __builtin_amdgcn_perm(er[1], er[0], 0x07060302u);
            pk.y = __builtin_amdgcn_perm(er[3], er[2], 0x07060302u);
            *(uint2*)&Ps[q * 72 + mt * 16 + quad * 4] = pk;   // wave-private strip
        }
        // no barrier: P strips are wave-private; in-wave DS ordering + lgkmcnt suffice

        // PV: O = P * V  (A = P fragments, B = V^T tiles)
        bf16x8 pf0 = *(const bf16x8*)&Ps[q * 72 + quad * 8];
        bf16x8 pf1 = *(const bf16x8*)&Ps[q * 72 + 32 + quad * 8];
#pragma unroll
        for (int nt = 0; nt < 4; ++nt) {
            bf16x8 vf0 = *(const bf16x8*)&Vs[(nt * 16 + l16) * 72 + quad * 8];
            bf16x8 vf1 = *(const bf16x8*)&Vs[(nt * 16 + l16) * 72 + 32 + quad * 8];
            o_acc[nt] = __builtin_amdgcn_mfma_f32_16x16x32_bf16(pf0, vf0, o_acc[nt], 0, 0, 0);
            o_acc[nt] = __builtin_amdgcn_mfma_f32_16x16x32_bf16(pf1, vf1, o_acc[nt], 0, 0, 0);
        }
        // rotate mask prefetch
#pragma unroll
        for (int i = 0; i < 4; ++i) mc[i] = mn[i];
    }

    // final l reduction: sum across quads (lanes with same l16), then in-wave transpose
    l_part += __shfl_xor(l_part, 16);
    l_part += __shfl_xor(l_part, 32);
    l_lds[w * 16 + l16] = l_part;        // wave-private strip write
    // read pattern below is same-wave; compiler orders DS ops

#pragma unroll
    for (int reg = 0; reg < 4; ++reg) {
        int row = w * 16 + quad * 4 + reg;
        float inv = 1.0f / l_lds[row];
        int sidx = s0 + row;
        u16* dst = aout + ((size_t)(b * S_LEN + sidx)) * HID + (g * R_REP + r) * HD;
#pragma unroll
        for (int nt = 0; nt < 4; ++nt)
            dst[nt * 16 + l16] = f2bf(o_acc[nt][reg] * inv);
    }
}

// ------- Output GEMM: BM=64 BN=128, 512 blocks (2/CU); dbuf + XOR-swizzled LDS;
//         fp32 out + bias + residual -------
__global__ __launch_bounds__(256) void gemm_o(const u16* __restrict__ A,
                                              const u16* __restrict__ WT,
                                              const float* __restrict__ bo,
                                              const float* __restrict__ Xres,
                                              float* __restrict__ out) {
    __shared__ __align__(16) u16 As[2][64 * 32];
    __shared__ __align__(16) u16 Bs[2][128 * 32];
    int tid = threadIdx.x;
    int w = tid >> 6, lane = tid & 63, quad = lane >> 4, l16 = lane & 15;
    int m0 = blockIdx.y * 64, n0 = blockIdx.x * 128;
    int wr = (w >> 1) * 32, wc = (w & 1) * 64;
    int srow = lane >> 2;
    int scol = (((lane & 3) ^ ((lane >> 3) & 3)) * 8);   // swizzled global source col

    const u16* aP  = &A[(size_t)(m0 + w * 16 + srow) * 2048 + scol];
    const u16* bP0 = &WT[(size_t)(n0 + w * 32 + srow) * 2048 + scol];
    const u16* bP1 = bP0 + (size_t)16 * 2048;

    f32x4 acc[2][4];
#pragma unroll
    for (int i = 0; i < 2; ++i)
#pragma unroll
        for (int j = 0; j < 4; ++j) acc[i][j] = (f32x4){0.f, 0.f, 0.f, 0.f};

    gload_lds16(aP,  &As[0][(w * 16) * 32]);
    gload_lds16(bP0, &Bs[0][(w * 32) * 32]);
    gload_lds16(bP1, &Bs[0][(w * 32 + 16) * 32]);
    __syncthreads();

    int rcol = (quad ^ ((l16 >> 1) & 3)) * 8;   // swizzled fragment-read col
    int cur = 0;
    for (int k0 = 0; k0 < 2048; k0 += 32) {
        int kn = k0 + 32;
        if (kn < 2048) {
            gload_lds16(aP + kn,  &As[cur ^ 1][(w * 16) * 32]);
            gload_lds16(bP0 + kn, &Bs[cur ^ 1][(w * 32) * 32]);
            gload_lds16(bP1 + kn, &Bs[cur ^ 1][(w * 32 + 16) * 32]);
        }
        bf16x8 af[2], bfr[4];
#pragma unroll
        for (int mt = 0; mt < 2; ++mt)
            af[mt] = *(const bf16x8*)&As[cur][(wr + mt * 16 + l16) * 32 + rcol];
#pragma unroll
        for (int nt = 0; nt < 4; ++nt)
            bfr[nt] = *(const bf16x8*)&Bs[cur][(wc + nt * 16 + l16) * 32 + rcol];
#pragma unroll
        for (int mt = 0; mt < 2; ++mt)
#pragma unroll
            for (int nt = 0; nt < 4; ++nt)
                acc[mt][nt] = __builtin_amdgcn_mfma_f32_16x16x32_bf16(af[mt], bfr[nt], acc[mt][nt], 0, 0, 0);
        __syncthreads();
        cur ^= 1;
    }

#pragma unroll
    for (int nt = 0; nt < 4; ++nt) {
        int n = n0 + wc + nt * 16 + l16;
        float bias = bo[n];
#pragma unroll
        for (int mt = 0; mt < 2; ++mt) {
#pragma unroll
            for (int reg = 0; reg < 4; ++reg) {
                int m = m0 + wr + mt * 16 + quad * 4 + reg;
                out[(size_t)m * 2048 + n] = acc[mt][nt][reg] + bias + Xres[(size_t)m * 2048 + n];
            }
        }
    }
}

extern "C" void kernel_launch(void* const* d_in, const int* in_sizes, int n_in,
                              void* d_out, int out_size, void* d_ws, size_t ws_size,
                              hipStream_t stream) {
    const float* x    = (const float*)d_in[0];
    const float* mask = (const float*)d_in[1];
    const float* Wq   = (const float*)d_in[2];
    const float* bq   = (const float*)d_in[3];
    const float* Wk   = (const float*)d_in[4];
    const float* bk   = (const float*)d_in[5];
    const float* Wv   = (const float*)d_in[6];
    const float* bv   = (const float*)d_in[7];
    const float* Wo   = (const float*)d_in[8];
    const float* bo   = (const float*)d_in[9];
    float* out = (float*)d_out;

    u16* ws = (u16*)d_ws;
    size_t off = 0;
    u16* WqkvT = ws + off; off += (size_t)NQKV * 2048;
    u16* WoT   = ws + off; off += (size_t)2048 * 2048;
    u16* q_buf = ws + off; off += (size_t)BATCH * G_KV * R_REP * S_LEN * HD;
    u16* k_buf = ws + off; off += (size_t)BATCH * G_KV * S_LEN * HD;
    u16* v_buf = ws + off; off += (size_t)BATCH * G_KV * S_LEN * HD;  // transposed [b][g][d][s]
    u16* a_out = ws + off; off += (size_t)2048 * 2048;
    u16* Xb       = a_out;            // alias: consumed by gemm_qkv before attn writes a_out
    float* mask_pm = (float*)WqkvT;   // alias: WqkvT (12.6 MB) dead after gemm_qkv; need 8 MB

    cvt_x<<<dim3(2048 * 2048 / (256 * 8)), 256, 0, stream>>>(x, Xb);

    dim3 tb(32, 8);
    transpose_qkv<<<dim3(96, 64), tb, 0, stream>>>(Wq, Wk, Wv, WqkvT);
    transpose_cvt<<<dim3(64, 64), tb, 0, stream>>>(Wo, WoT, 2048, 2048);

    gemm_qkv<<<dim3(NQKV / 96, 2048 / 128), 256, 0, stream>>>(Xb, WqkvT, bq, bk, bv,
                                                              q_buf, k_buf, v_buf);

    mask_perm<<<dim3(BATCH * 16 * 16), 256, 0, stream>>>(mask, mask_pm);

    attn_mfma<<<dim3(BATCH * G_KV * R_REP * (S_LEN / 64)), 256, 0, stream>>>(
        q_buf, k_buf, v_buf, mask_pm, a_out);

    gemm_o<<<dim3(2048 / 128, 2048 / 64), 256, 0, stream>>>(a_out, WoT, bo, x, out);
}